// Round 9
// baseline (360.201 us; speedup 1.0000x reference)
//
#include <hip/hip_runtime.h>

#define NPART 1000000
#define NGRID 128
#define NNODES (NGRID * NGRID)
#define NBINS 64               // 8x8 tiles of 16x16 nodes
#define BINCAP 26624           // fixed slab capacity (max expected ~24.9K)
#define SUBW 18                // 16 + 2 halo (high side)
#define SUBN (SUBW * SUBW)     // 324
#define P2G_SUB 8              // sub-blocks per tile
#define P2G_THREADS 1024
#define PS_CHUNK 4             // 1024 particles/block
#define PS_BLOCKS 977          // ceil(1e6 / (256*4))
#define PS_PART (256 * PS_CHUNK)
#define G2P_THREADS 1024
#define G2P_BLOCKS 256         // 1 block/CU; full grid staged in 128 KiB LDS

// Output flat offsets (floats), return order: x, v, C, F, material, Jp
#define OUT_X   0
#define OUT_V   2000000
#define OUT_C   4000000
#define OUT_F   8000000
#define OUT_MAT 12000000
#define OUT_JP  13000000

__device__ __forceinline__ void quad_weights(float fx, float w[3]) {
    w[0] = 0.5f * (1.5f - fx) * (1.5f - fx);
    w[1] = 0.75f - (fx - 1.0f) * (fx - 1.0f);
    w[2] = 0.5f * (fx - 0.5f) * (fx - 0.5f);
}

struct PhysOut {
    float o00, o01, o10, o11;      // projected F (output)
    float aff00, aff01, aff10, aff11;
    float mom0, mom1;
    float jp_new;
};

// Trig-free closed-form 2x2 SVD consumer.
__device__ __forceinline__ PhysOut particle_phys(
    float2 xx, float2 vv, float4 Cm, float4 Fin, int mat, float jp)
{
    const float DT = 1e-4f;
    const float P_MASS = 1.52587890625e-05f;
    const float MU_0 = (float)(1000.0 / (2.0 * 1.2));
    const float LAMBDA_0 = (float)(200.0 / 0.72);
    const float SCALE = -1e-4f;   // -DT*P_VOL*4*INV_DX^2 == -DT exactly

    float F00 = Fin.x + DT * (Cm.x * Fin.x + Cm.y * Fin.z);
    float F01 = Fin.y + DT * (Cm.x * Fin.y + Cm.y * Fin.w);
    float F10 = Fin.z + DT * (Cm.z * Fin.x + Cm.w * Fin.z);
    float F11 = Fin.w + DT * (Cm.z * Fin.y + Cm.w * Fin.w);

    float h = (mat == 1) ? 0.3f : expf(10.0f * (1.0f - jp));
    float mu = (mat == 0) ? 0.0f : MU_0 * h;
    float lam = LAMBDA_0 * h;

    float Es = 0.5f * (F00 + F11), Fs = 0.5f * (F00 - F11);
    float Gs = 0.5f * (F01 + F10), Hs = 0.5f * (F10 - F01);
    float q2 = Es * Es + Hs * Hs;
    float r2 = Fs * Fs + Gs * Gs;
    float Qs = sqrtf(q2);
    float Rs = sqrtf(r2);
    float s1 = Qs + Rs, s2 = Qs - Rs;
    float cdif = 1.0f, sdif = 0.0f;
    if (q2 > 1e-30f) { float rq = 1.0f / Qs; cdif = Es * rq; sdif = Hs * rq; }
    float csum = 1.0f, ssum = 0.0f;
    if (r2 > 1e-30f) { float rr = 1.0f / Rs; csum = Fs * rr; ssum = Gs * rr; }
    float cucv = 0.5f * (cdif + csum);
    float susv = 0.5f * (cdif - csum);
    float cusv = 0.5f * (ssum - sdif);
    float sucv = 0.5f * (ssum + sdif);

    float c1 = fminf(fmaxf(s1, 1.0f - 2.5e-2f), 1.0f + 4.5e-3f);
    float c2 = fminf(fmaxf(s2, 1.0f - 2.5e-2f), 1.0f + 4.5e-3f);
    float jp_new = jp;
    float sg1 = s1, sg2 = s2;
    if (mat == 2) {
        jp_new = jp * (s1 / c1) * (s2 / c2);
        sg1 = c1;
        sg2 = c2;
    }
    float J = sg1 * sg2;

    float R00 = cdif, R01 = -sdif;
    float R10 = sdif, R11 = cdif;

    float o00, o01, o10, o11;
    if (mat == 0) {
        float sq = sqrtf(J);
        o00 = sq; o01 = 0.0f; o10 = 0.0f; o11 = sq;
    } else if (mat == 2) {
        o00 = sg1 * cucv + sg2 * susv;
        o01 = sg1 * cusv - sg2 * sucv;
        o10 = sg1 * sucv - sg2 * cusv;
        o11 = sg1 * susv + sg2 * cucv;
    } else {
        o00 = F00; o01 = F01; o10 = F10; o11 = F11;
    }

    float A00 = o00 - R00, A01 = o01 - R01, A10 = o10 - R10, A11 = o11 - R11;
    float S00 = A00 * o00 + A01 * o01;
    float S01 = A00 * o10 + A01 * o11;
    float S10 = A10 * o00 + A11 * o01;
    float S11 = A10 * o10 + A11 * o11;
    float ljj = lam * J * (J - 1.0f);

    PhysOut po;
    po.o00 = o00; po.o01 = o01; po.o10 = o10; po.o11 = o11;
    po.aff00 = SCALE * (2.0f * mu * S00 + ljj) + P_MASS * Cm.x;
    po.aff01 = SCALE * (2.0f * mu * S01)       + P_MASS * Cm.y;
    po.aff10 = SCALE * (2.0f * mu * S10)       + P_MASS * Cm.z;
    po.aff11 = SCALE * (2.0f * mu * S11 + ljj) + P_MASS * Cm.w;
    po.mom0 = P_MASS * vv.x - (po.aff00 * xx.x + po.aff01 * xx.y);
    po.mom1 = P_MASS * vv.y - (po.aff10 * xx.x + po.aff11 * xx.y);
    po.jp_new = jp_new;
    return po;
}

__device__ __forceinline__ int tile_of(float2 xx) {
    int b0 = (int)floorf(xx.x * 128.0f - 0.5f);
    int b1 = (int)floorf(xx.y * 128.0f - 0.5f);
    return ((b0 >> 4) << 3) | (b1 >> 4);
}

// ---- Pass 1: physics + direct slab-record scatter + F/mat/Jp outputs ----
__global__ __launch_bounds__(256) void phys_scatter_kernel(
    const float2* __restrict__ x, const float2* __restrict__ v,
    const float4* __restrict__ C, const float4* __restrict__ F,
    const int* __restrict__ material, const float* __restrict__ Jp,
    int* __restrict__ binCursor, float* __restrict__ out, float4* __restrict__ rec)
{
    __shared__ int lh[NBINS];
    __shared__ int lbase[NBINS];
    int tid = threadIdx.x;
    if (tid < NBINS) lh[tid] = 0;
    __syncthreads();
    int base = blockIdx.x * PS_PART;

    float2 xs[PS_CHUNK], vs[PS_CHUNK];
    float4 Cs[PS_CHUNK], Fs[PS_CHUNK];
    float jps[PS_CHUNK];
    int ms[PS_CHUNK], pk[PS_CHUNK];

    #pragma unroll
    for (int c = 0; c < PS_CHUNK; ++c) {
        int n = base + c * 256 + tid;
        if (n < NPART) {
            xs[c] = x[n]; vs[c] = v[n]; Cs[c] = C[n]; Fs[c] = F[n];
            ms[c] = material[n]; jps[c] = Jp[n];
            int t = tile_of(xs[c]);
            int r = atomicAdd(&lh[t], 1);
            pk[c] = (t << 16) | r;
        } else pk[c] = -1;
    }
    __syncthreads();
    if (tid < NBINS) {
        int c = lh[tid];
        lbase[tid] = c ? atomicAdd(&binCursor[tid], c) : 0;
    }
    __syncthreads();

    #pragma unroll
    for (int c = 0; c < PS_CHUNK; ++c) {
        if (pk[c] < 0) continue;
        int n = base + c * 256 + tid;
        PhysOut po = particle_phys(xs[c], vs[c], Cs[c], Fs[c], ms[c], jps[c]);
        ((float4*)(out + OUT_F))[n] = make_float4(po.o00, po.o01, po.o10, po.o11);
        out[OUT_MAT + n] = (float)ms[c];
        out[OUT_JP + n] = po.jp_new;
        int t = pk[c] >> 16, r = pk[c] & 0xffff;
        int pos = t * BINCAP + lbase[t] + r;
        rec[2 * pos]     = make_float4(xs[c].x, xs[c].y, po.mom0, po.mom1);
        rec[2 * pos + 1] = make_float4(po.aff00, po.aff01, po.aff10, po.aff11);
    }
}

// ---- Pass 2: tiled P2G with NATIVE f32 LDS atomics (ds_add_f32 via
//      unsafeAtomicAdd: single-bank, no-return; NOT the r4 CAS loop).
//      Flush: native f32 global atomics into per-node accumulators. ----
__global__ __launch_bounds__(P2G_THREADS) void p2g_kernel(
    const float4* __restrict__ rec, const int* __restrict__ binCursor,
    float* __restrict__ raw_v0, float* __restrict__ raw_v1,
    float* __restrict__ raw_m)
{
    __shared__ float s_v0[SUBN], s_v1[SUBN], s_m[SUBN];
    int tid = threadIdx.x;
    int tile = blockIdx.x >> 3;
    int sub  = blockIdx.x & (P2G_SUB - 1);
    for (int i = tid; i < SUBN; i += P2G_THREADS) {
        s_v0[i] = 0.f; s_v1[i] = 0.f; s_m[i] = 0.f;
    }
    __syncthreads();
    int start = tile * BINCAP;
    int cnt = binCursor[tile];
    int t0 = (tile >> 3) << 4;
    int t1 = (tile & 7) << 4;
    const float DX = 1.0f / 128.0f;

    for (int p = sub * P2G_THREADS + tid; p < cnt; p += P2G_SUB * P2G_THREADS) {
        float4 r0 = rec[2 * (start + p)];
        float4 r1 = rec[2 * (start + p) + 1];
        float xg0 = r0.x * 128.0f, xg1 = r0.y * 128.0f;
        int b0 = (int)floorf(xg0 - 0.5f), b1 = (int)floorf(xg1 - 0.5f);
        float fx0 = xg0 - (float)b0, fx1 = xg1 - (float)b1;
        float wx[3], wy[3];
        quad_weights(fx0, wx);
        quad_weights(fx1, wy);
        int l0 = b0 - t0, l1 = b1 - t1;
        #pragma unroll
        for (int i = 0; i < 3; ++i) {
            float nx0 = (float)(b0 + i) * DX;
            #pragma unroll
            for (int j = 0; j < 3; ++j) {
                float wt = wx[i] * wy[j];
                float nx1 = (float)(b1 + j) * DX;
                int l = (l0 + i) * SUBW + (l1 + j);
                unsafeAtomicAdd(&s_v0[l], wt * (r0.z + r1.x * nx0 + r1.y * nx1));
                unsafeAtomicAdd(&s_v1[l], wt * (r0.w + r1.z * nx0 + r1.w * nx1));
                unsafeAtomicAdd(&s_m[l], wt);
            }
        }
    }
    __syncthreads();
    // flush: native f32 global atomics straight into per-node accumulators
    for (int l = tid; l < SUBN; l += P2G_THREADS) {
        float a0 = s_v0[l], a1 = s_v1[l], am = s_m[l];
        if (a0 == 0.f && a1 == 0.f && am == 0.f) continue;
        int li = l / SUBW, lj = l - li * SUBW;
        int g0 = t0 + li, g1 = t1 + lj;
        if (g0 >= NGRID || g1 >= NGRID) continue;   // halo past grid edge
        int g = g0 * NGRID + g1;
        unsafeAtomicAdd(&raw_v0[g], a0);
        unsafeAtomicAdd(&raw_v1[g], a1);
        unsafeAtomicAdd(&raw_m[g], am);
    }
}

// ---- Pass 3: normalize+gravity+clamp fused into G2P staging (full grid in LDS) ----
__global__ __launch_bounds__(G2P_THREADS) void g2p_kernel(
    const float2* __restrict__ x,
    const float* __restrict__ raw_v0,
    const float* __restrict__ raw_v1,
    const float* __restrict__ raw_m,
    float* __restrict__ out)
{
    __shared__ float2 s_g[NNODES];   // 128 KiB
    int tid = threadIdx.x;
    const float P_MASS = 1.52587890625e-05f;

    for (int idx = tid; idx < NNODES; idx += G2P_THREADS) {
        float s0 = raw_v0[idx];
        float s1 = raw_v1[idx];
        float sw = raw_m[idx];
        int gi = idx >> 7, gj = idx & 127;
        float m = sw * P_MASS;
        if (m > 0.f) {
            float rm = 1.0f / m;
            s0 *= rm;
            s1 *= rm;
            s1 -= 5e-3f;   // -DT*50 gravity
        }
        if (gi < 3) s0 = fmaxf(s0, 0.0f);
        if (gi >= NGRID - 2) s0 = fminf(s0, 0.0f);
        if (gj < 3) s1 = fmaxf(s1, 0.0f);
        if (gj >= NGRID - 2) s1 = fminf(s1, 0.0f);
        s_g[idx] = make_float2(s0, s1);
    }
    __syncthreads();

    const float DX = 1.0f / 128.0f;
    const float DT = 1e-4f;
    const float K4 = 65536.0f;

    for (int n = blockIdx.x * G2P_THREADS + tid; n < NPART;
         n += G2P_BLOCKS * G2P_THREADS) {
        float2 xx = x[n];
        float xg0 = xx.x * 128.0f, xg1 = xx.y * 128.0f;
        int b0 = (int)floorf(xg0 - 0.5f), b1 = (int)floorf(xg1 - 0.5f);
        float fx0 = xg0 - (float)b0, fx1 = xg1 - (float)b1;
        float wx[3], wy[3];
        quad_weights(fx0, wx);
        quad_weights(fx1, wy);

        float nv0 = 0.f, nv1 = 0.f;
        float nC00 = 0.f, nC01 = 0.f, nC10 = 0.f, nC11 = 0.f;
        #pragma unroll
        for (int i = 0; i < 3; ++i) {
            float node0 = (float)(b0 + i) * DX;
            #pragma unroll
            for (int j = 0; j < 3; ++j) {
                float wt = wx[i] * wy[j];
                float2 g = s_g[(b0 + i) * NGRID + (b1 + j)];
                float node1 = (float)(b1 + j) * DX;
                nv0 += wt * g.x;
                nv1 += wt * g.y;
                nC00 += wt * g.x * node0;
                nC01 += wt * g.x * node1;
                nC10 += wt * g.y * node0;
                nC11 += wt * g.y * node1;
            }
        }
        nC00 = (nC00 - nv0 * xx.x) * K4;
        nC01 = (nC01 - nv0 * xx.y) * K4;
        nC10 = (nC10 - nv1 * xx.x) * K4;
        nC11 = (nC11 - nv1 * xx.y) * K4;

        ((float2*)(out + OUT_X))[n] = make_float2(xx.x + DT * nv0, xx.y + DT * nv1);
        ((float2*)(out + OUT_V))[n] = make_float2(nv0, nv1);
        ((float4*)(out + OUT_C))[n] = make_float4(nC00, nC01, nC10, nC11);
    }
}

extern "C" void kernel_launch(void* const* d_in, const int* in_sizes, int n_in,
                              void* d_out, int out_size, void* d_ws, size_t ws_size,
                              hipStream_t stream)
{
    const float2* x = (const float2*)d_in[0];
    const float2* v = (const float2*)d_in[1];
    const float4* C = (const float4*)d_in[2];
    const float4* F = (const float4*)d_in[3];
    const int* material = (const int*)d_in[4];
    const float* Jp = (const float*)d_in[5];
    float* out = (float*)d_out;

    // workspace layout:
    //   [0,256B)          binCursor (64 ints)
    //   [4KB, +192KB)     raw: 3 x f32 x 16384 node accumulators
    //   [4MB, +54.5MB)    rec slabs
    int* binCursor = (int*)d_ws;
    float* raw_v0 = (float*)((char*)d_ws + 4096);
    float* raw_v1 = raw_v0 + NNODES;
    float* raw_m  = raw_v1 + NNODES;
    float4* rec = (float4*)((char*)d_ws + (4 << 20));           // 4 MB

    // zero binCursor + the three raw accumulator arrays in one memset
    hipMemsetAsync(d_ws, 0, 4096 + 3 * NNODES * sizeof(float), stream);

    phys_scatter_kernel<<<PS_BLOCKS, 256, 0, stream>>>(x, v, C, F, material, Jp,
                                                       binCursor, out, rec);
    p2g_kernel<<<NBINS * P2G_SUB, P2G_THREADS, 0, stream>>>(rec, binCursor,
                                                            raw_v0, raw_v1, raw_m);
    g2p_kernel<<<G2P_BLOCKS, G2P_THREADS, 0, stream>>>(x, raw_v0, raw_v1, raw_m, out);
}

// Round 10
// 165.767 us; speedup vs baseline: 2.1729x; 2.1729x over previous
//
#include <hip/hip_runtime.h>

#define NPART 1000000
#define NGRID 128
#define NNODES (NGRID * NGRID)
#define NBINS 64               // 8x8 tiles of 16x16 nodes
#define BINCAP 26624           // fixed slab capacity (max expected ~24.9K)
#define SUBW 18                // 16 + 2 halo (high side)
#define SUBN (SUBW * SUBW)     // 324
#define P2G_SUB 8              // sub-blocks per tile
#define P2G_THREADS 512
#define PS_CHUNK 4             // 1024 particles/block
#define PS_BLOCKS 977          // ceil(1e6 / (256*4))
#define PS_PART (256 * PS_CHUNK)
#define G2P_THREADS 1024
#define G2P_BLOCKS 256         // 1 block/CU; full grid staged in 128 KiB LDS

// fixed-point scales (integer atomics, exact/associative)
// f32 LDS atomics are POISON on this toolchain: both atomicAdd(float*) [r4]
// and unsafeAtomicAdd [r9] compile to CAS retry loops (221-466 us p2g).
#define FPSCALE 281474976710656.0f      // 2^48 (velocity, int64)
#define FPINV   3.552713678800501e-15   // 2^-48 (double)
#define WSCALE  16777216.0f             // 2^24 (weight sum)
#define WINV    5.9604644775390625e-8   // 2^-24

// Output flat offsets (floats), return order: x, v, C, F, material, Jp
#define OUT_X   0
#define OUT_V   2000000
#define OUT_C   4000000
#define OUT_F   8000000
#define OUT_MAT 12000000
#define OUT_JP  13000000

__device__ __forceinline__ void quad_weights(float fx, float w[3]) {
    w[0] = 0.5f * (1.5f - fx) * (1.5f - fx);
    w[1] = 0.75f - (fx - 1.0f) * (fx - 1.0f);
    w[2] = 0.5f * (fx - 0.5f) * (fx - 0.5f);
}

struct PhysOut {
    float o00, o01, o10, o11;      // projected F (output)
    float aff00, aff01, aff10, aff11;
    float mom0, mom1;
    float jp_new;
};

// Trig-free closed-form 2x2 SVD consumer.
__device__ __forceinline__ PhysOut particle_phys(
    float2 xx, float2 vv, float4 Cm, float4 Fin, int mat, float jp)
{
    const float DT = 1e-4f;
    const float P_MASS = 1.52587890625e-05f;
    const float MU_0 = (float)(1000.0 / (2.0 * 1.2));
    const float LAMBDA_0 = (float)(200.0 / 0.72);
    const float SCALE = -1e-4f;   // -DT*P_VOL*4*INV_DX^2 == -DT exactly

    float F00 = Fin.x + DT * (Cm.x * Fin.x + Cm.y * Fin.z);
    float F01 = Fin.y + DT * (Cm.x * Fin.y + Cm.y * Fin.w);
    float F10 = Fin.z + DT * (Cm.z * Fin.x + Cm.w * Fin.z);
    float F11 = Fin.w + DT * (Cm.z * Fin.y + Cm.w * Fin.w);

    float h = (mat == 1) ? 0.3f : expf(10.0f * (1.0f - jp));
    float mu = (mat == 0) ? 0.0f : MU_0 * h;
    float lam = LAMBDA_0 * h;

    float Es = 0.5f * (F00 + F11), Fs = 0.5f * (F00 - F11);
    float Gs = 0.5f * (F01 + F10), Hs = 0.5f * (F10 - F01);
    float q2 = Es * Es + Hs * Hs;
    float r2 = Fs * Fs + Gs * Gs;
    float Qs = sqrtf(q2);
    float Rs = sqrtf(r2);
    float s1 = Qs + Rs, s2 = Qs - Rs;
    float cdif = 1.0f, sdif = 0.0f;
    if (q2 > 1e-30f) { float rq = 1.0f / Qs; cdif = Es * rq; sdif = Hs * rq; }
    float csum = 1.0f, ssum = 0.0f;
    if (r2 > 1e-30f) { float rr = 1.0f / Rs; csum = Fs * rr; ssum = Gs * rr; }
    float cucv = 0.5f * (cdif + csum);
    float susv = 0.5f * (cdif - csum);
    float cusv = 0.5f * (ssum - sdif);
    float sucv = 0.5f * (ssum + sdif);

    float c1 = fminf(fmaxf(s1, 1.0f - 2.5e-2f), 1.0f + 4.5e-3f);
    float c2 = fminf(fmaxf(s2, 1.0f - 2.5e-2f), 1.0f + 4.5e-3f);
    float jp_new = jp;
    float sg1 = s1, sg2 = s2;
    if (mat == 2) {
        jp_new = jp * (s1 / c1) * (s2 / c2);
        sg1 = c1;
        sg2 = c2;
    }
    float J = sg1 * sg2;

    float R00 = cdif, R01 = -sdif;
    float R10 = sdif, R11 = cdif;

    float o00, o01, o10, o11;
    if (mat == 0) {
        float sq = sqrtf(J);
        o00 = sq; o01 = 0.0f; o10 = 0.0f; o11 = sq;
    } else if (mat == 2) {
        o00 = sg1 * cucv + sg2 * susv;
        o01 = sg1 * cusv - sg2 * sucv;
        o10 = sg1 * sucv - sg2 * cusv;
        o11 = sg1 * susv + sg2 * cucv;
    } else {
        o00 = F00; o01 = F01; o10 = F10; o11 = F11;
    }

    float A00 = o00 - R00, A01 = o01 - R01, A10 = o10 - R10, A11 = o11 - R11;
    float S00 = A00 * o00 + A01 * o01;
    float S01 = A00 * o10 + A01 * o11;
    float S10 = A10 * o00 + A11 * o01;
    float S11 = A10 * o10 + A11 * o11;
    float ljj = lam * J * (J - 1.0f);

    PhysOut po;
    po.o00 = o00; po.o01 = o01; po.o10 = o10; po.o11 = o11;
    po.aff00 = SCALE * (2.0f * mu * S00 + ljj) + P_MASS * Cm.x;
    po.aff01 = SCALE * (2.0f * mu * S01)       + P_MASS * Cm.y;
    po.aff10 = SCALE * (2.0f * mu * S10)       + P_MASS * Cm.z;
    po.aff11 = SCALE * (2.0f * mu * S11 + ljj) + P_MASS * Cm.w;
    po.mom0 = P_MASS * vv.x - (po.aff00 * xx.x + po.aff01 * xx.y);
    po.mom1 = P_MASS * vv.y - (po.aff10 * xx.x + po.aff11 * xx.y);
    po.jp_new = jp_new;
    return po;
}

__device__ __forceinline__ int tile_of(float2 xx) {
    int b0 = (int)floorf(xx.x * 128.0f - 0.5f);
    int b1 = (int)floorf(xx.y * 128.0f - 0.5f);
    return ((b0 >> 4) << 3) | (b1 >> 4);
}

// ---- Pass 1: physics + LDS-staged tile-sorted rec write + F/mat/Jp outputs ----
__global__ __launch_bounds__(256) void phys_scatter_kernel(
    const float2* __restrict__ x, const float2* __restrict__ v,
    const float4* __restrict__ C, const float4* __restrict__ F,
    const int* __restrict__ material, const float* __restrict__ Jp,
    int* __restrict__ binCursor, float* __restrict__ out, float4* __restrict__ rec)
{
    __shared__ int lh[NBINS];      // per-tile count in this block
    __shared__ int lpre[NBINS];    // exclusive prefix (block-local)
    __shared__ int lbase[NBINS];   // global slot base for this tile (incl. t*BINCAP)
    __shared__ int s_total;
    __shared__ float4 srec0[PS_PART];
    __shared__ float4 srec1[PS_PART];
    __shared__ int spos[PS_PART];

    int tid = threadIdx.x;
    if (tid < NBINS) lh[tid] = 0;
    __syncthreads();
    int base = blockIdx.x * PS_PART;

    float2 xs[PS_CHUNK], vs[PS_CHUNK];
    float4 Cs[PS_CHUNK], Fs[PS_CHUNK];
    float jps[PS_CHUNK];
    int ms[PS_CHUNK], pk[PS_CHUNK];

    #pragma unroll
    for (int c = 0; c < PS_CHUNK; ++c) {
        int n = base + c * 256 + tid;
        if (n < NPART) {
            xs[c] = x[n]; vs[c] = v[n]; Cs[c] = C[n]; Fs[c] = F[n];
            ms[c] = material[n]; jps[c] = Jp[n];
            int t = tile_of(xs[c]);
            int r = atomicAdd(&lh[t], 1);
            pk[c] = (t << 16) | r;
        } else pk[c] = -1;
    }
    __syncthreads();
    if (tid < NBINS) {
        int c = lh[tid];
        // inclusive scan across the 64 lanes of wave 0
        int inc = c;
        #pragma unroll
        for (int d = 1; d < 64; d <<= 1) {
            int y = __shfl_up(inc, d);
            if (tid >= d) inc += y;
        }
        lpre[tid] = inc - c;                 // exclusive prefix
        if (tid == NBINS - 1) s_total = inc; // block total
        lbase[tid] = tid * BINCAP + (c ? atomicAdd(&binCursor[tid], c) : 0);
    }
    __syncthreads();

    #pragma unroll
    for (int c = 0; c < PS_CHUNK; ++c) {
        if (pk[c] < 0) continue;
        int n = base + c * 256 + tid;
        PhysOut po = particle_phys(xs[c], vs[c], Cs[c], Fs[c], ms[c], jps[c]);
        ((float4*)(out + OUT_F))[n] = make_float4(po.o00, po.o01, po.o10, po.o11);
        out[OUT_MAT + n] = (float)ms[c];
        out[OUT_JP + n] = po.jp_new;
        int t = pk[c] >> 16, r = pk[c] & 0xffff;
        int loc = lpre[t] + r;               // block-local tile-sorted slot
        srec0[loc] = make_float4(xs[c].x, xs[c].y, po.mom0, po.mom1);
        srec1[loc] = make_float4(po.aff00, po.aff01, po.aff10, po.aff11);
        spos[loc] = lbase[t] + r;            // absolute record slot
    }
    __syncthreads();

    // coalesced copy-out: consecutive k -> consecutive pos within tile runs
    int total = s_total;
    for (int k = tid; k < total; k += 256) {
        int pos = spos[k];
        rec[2 * pos]     = srec0[k];
        rec[2 * pos + 1] = srec1[k];
    }
}

// ---- Pass 2: tiled P2G; u64/u32 fixed-point LDS atomics (single-instr,
//      associative, exact); flush adds into GLOBAL integer node accumulators ----
__global__ __launch_bounds__(P2G_THREADS) void p2g_kernel(
    const float4* __restrict__ rec, const int* __restrict__ binCursor,
    unsigned long long* __restrict__ raw_v0,
    unsigned long long* __restrict__ raw_v1,
    unsigned long long* __restrict__ raw_m)
{
    __shared__ unsigned long long s_v0[SUBN], s_v1[SUBN];
    __shared__ unsigned int s_m[SUBN];
    int tid = threadIdx.x;
    int tile = blockIdx.x >> 3;
    int sub  = blockIdx.x & (P2G_SUB - 1);
    for (int i = tid; i < SUBN; i += P2G_THREADS) {
        s_v0[i] = 0ull; s_v1[i] = 0ull; s_m[i] = 0u;
    }
    __syncthreads();
    int start = tile * BINCAP;
    int cnt = binCursor[tile];
    int t0 = (tile >> 3) << 4;
    int t1 = (tile & 7) << 4;
    const float DX = 1.0f / 128.0f;

    for (int p = sub * P2G_THREADS + tid; p < cnt; p += P2G_SUB * P2G_THREADS) {
        float4 r0 = rec[2 * (start + p)];
        float4 r1 = rec[2 * (start + p) + 1];
        float xg0 = r0.x * 128.0f, xg1 = r0.y * 128.0f;
        int b0 = (int)floorf(xg0 - 0.5f), b1 = (int)floorf(xg1 - 0.5f);
        float fx0 = xg0 - (float)b0, fx1 = xg1 - (float)b1;
        float wx[3], wy[3];
        quad_weights(fx0, wx);
        quad_weights(fx1, wy);
        int l0 = b0 - t0, l1 = b1 - t1;
        #pragma unroll
        for (int i = 0; i < 3; ++i) {
            float nx0 = (float)(b0 + i) * DX;
            #pragma unroll
            for (int j = 0; j < 3; ++j) {
                float wt = wx[i] * wy[j];
                float nx1 = (float)(b1 + j) * DX;
                int l = (l0 + i) * SUBW + (l1 + j);
                long long q0 = (long long)(wt * (r0.z + r1.x * nx0 + r1.y * nx1) * FPSCALE);
                long long q1 = (long long)(wt * (r0.w + r1.z * nx0 + r1.w * nx1) * FPSCALE);
                unsigned int qm = (unsigned int)(wt * WSCALE);
                atomicAdd(&s_v0[l], (unsigned long long)q0);
                atomicAdd(&s_v1[l], (unsigned long long)q1);
                atomicAdd(&s_m[l], qm);
            }
        }
    }
    __syncthreads();
    // flush: global integer atomics straight into per-node accumulators
    for (int l = tid; l < SUBN; l += P2G_THREADS) {
        unsigned long long a0 = s_v0[l], a1 = s_v1[l];
        unsigned long long am = (unsigned long long)s_m[l];
        if (!(a0 | a1 | am)) continue;
        int li = l / SUBW, lj = l - li * SUBW;
        int g0 = t0 + li, g1 = t1 + lj;
        if (g0 >= NGRID || g1 >= NGRID) continue;   // halo past grid edge
        int g = g0 * NGRID + g1;
        atomicAdd(&raw_v0[g], a0);
        atomicAdd(&raw_v1[g], a1);
        atomicAdd(&raw_m[g], am);
    }
}

// ---- Pass 3: normalize+gravity+clamp fused into G2P staging (full grid in LDS) ----
__global__ __launch_bounds__(G2P_THREADS) void g2p_kernel(
    const float2* __restrict__ x,
    const unsigned long long* __restrict__ raw_v0,
    const unsigned long long* __restrict__ raw_v1,
    const unsigned long long* __restrict__ raw_m,
    float* __restrict__ out)
{
    __shared__ float2 s_g[NNODES];   // 128 KiB
    int tid = threadIdx.x;
    const float P_MASS = 1.52587890625e-05f;

    for (int idx = tid; idx < NNODES; idx += G2P_THREADS) {
        float s0 = (float)((double)(long long)raw_v0[idx] * FPINV);
        float s1 = (float)((double)(long long)raw_v1[idx] * FPINV);
        float sw = (float)((double)raw_m[idx] * WINV);
        int gi = idx >> 7, gj = idx & 127;
        float m = sw * P_MASS;
        if (m > 0.f) {
            float rm = 1.0f / m;
            s0 *= rm;
            s1 *= rm;
            s1 -= 5e-3f;   // -DT*50 gravity
        }
        if (gi < 3) s0 = fmaxf(s0, 0.0f);
        if (gi >= NGRID - 2) s0 = fminf(s0, 0.0f);
        if (gj < 3) s1 = fmaxf(s1, 0.0f);
        if (gj >= NGRID - 2) s1 = fminf(s1, 0.0f);
        s_g[idx] = make_float2(s0, s1);
    }
    __syncthreads();

    const float DX = 1.0f / 128.0f;
    const float DT = 1e-4f;
    const float K4 = 65536.0f;

    for (int n = blockIdx.x * G2P_THREADS + tid; n < NPART;
         n += G2P_BLOCKS * G2P_THREADS) {
        float2 xx = x[n];
        float xg0 = xx.x * 128.0f, xg1 = xx.y * 128.0f;
        int b0 = (int)floorf(xg0 - 0.5f), b1 = (int)floorf(xg1 - 0.5f);
        float fx0 = xg0 - (float)b0, fx1 = xg1 - (float)b1;
        float wx[3], wy[3];
        quad_weights(fx0, wx);
        quad_weights(fx1, wy);

        float nv0 = 0.f, nv1 = 0.f;
        float nC00 = 0.f, nC01 = 0.f, nC10 = 0.f, nC11 = 0.f;
        #pragma unroll
        for (int i = 0; i < 3; ++i) {
            float node0 = (float)(b0 + i) * DX;
            #pragma unroll
            for (int j = 0; j < 3; ++j) {
                float wt = wx[i] * wy[j];
                float2 g = s_g[(b0 + i) * NGRID + (b1 + j)];
                float node1 = (float)(b1 + j) * DX;
                nv0 += wt * g.x;
                nv1 += wt * g.y;
                nC00 += wt * g.x * node0;
                nC01 += wt * g.x * node1;
                nC10 += wt * g.y * node0;
                nC11 += wt * g.y * node1;
            }
        }
        nC00 = (nC00 - nv0 * xx.x) * K4;
        nC01 = (nC01 - nv0 * xx.y) * K4;
        nC10 = (nC10 - nv1 * xx.x) * K4;
        nC11 = (nC11 - nv1 * xx.y) * K4;

        ((float2*)(out + OUT_X))[n] = make_float2(xx.x + DT * nv0, xx.y + DT * nv1);
        ((float2*)(out + OUT_V))[n] = make_float2(nv0, nv1);
        ((float4*)(out + OUT_C))[n] = make_float4(nC00, nC01, nC10, nC11);
    }
}

extern "C" void kernel_launch(void* const* d_in, const int* in_sizes, int n_in,
                              void* d_out, int out_size, void* d_ws, size_t ws_size,
                              hipStream_t stream)
{
    const float2* x = (const float2*)d_in[0];
    const float2* v = (const float2*)d_in[1];
    const float4* C = (const float4*)d_in[2];
    const float4* F = (const float4*)d_in[3];
    const int* material = (const int*)d_in[4];
    const float* Jp = (const float*)d_in[5];
    float* out = (float*)d_out;

    // workspace layout:
    //   [0,256B)          binCursor (64 ints)
    //   [4KB, +384KB)     raw: 3 x u64 x 16384 node accumulators
    //   [4MB, +54.5MB)    rec slabs
    int* binCursor = (int*)d_ws;
    unsigned long long* raw_v0 = (unsigned long long*)((char*)d_ws + 4096);
    unsigned long long* raw_v1 = raw_v0 + NNODES;
    unsigned long long* raw_m  = raw_v1 + NNODES;
    float4* rec = (float4*)((char*)d_ws + (4 << 20));           // 4 MB

    // zero binCursor + the three raw accumulator arrays in one memset
    hipMemsetAsync(d_ws, 0, 4096 + 3 * NNODES * sizeof(unsigned long long), stream);

    phys_scatter_kernel<<<PS_BLOCKS, 256, 0, stream>>>(x, v, C, F, material, Jp,
                                                       binCursor, out, rec);
    p2g_kernel<<<NBINS * P2G_SUB, P2G_THREADS, 0, stream>>>(rec, binCursor,
                                                            raw_v0, raw_v1, raw_m);
    g2p_kernel<<<G2P_BLOCKS, G2P_THREADS, 0, stream>>>(x, raw_v0, raw_v1, raw_m, out);
}